// Round 1
// baseline (157.896 us; speedup 1.0000x reference)
//
#include <hip/hip_runtime.h>
#include <hip/hip_bf16.h>

// Problem constants (from reference): B=16, TV=128, TH=64, F=512, H=512, D=256
#define BB 16
#define TV 128
#define TH 64
#define FF 512
#define HH 512
#define DD 256

// ---------------------------------------------------------------------------
// Tiled fp32 GEMM: C[M,N] = A[M,K] * Bm[K,N] (+ bias[N])
// K=512, N=256 fixed. 64x64 tile, BK=16, 256 threads, 4x4 per thread.
// ---------------------------------------------------------------------------
__global__ __launch_bounds__(256) void gemm_bias_kernel(
    const float* __restrict__ A, const float* __restrict__ Bm,
    const float* __restrict__ bias, float* __restrict__ C, int K, int N) {
  const int m0 = blockIdx.y * 64;
  const int n0 = blockIdx.x * 64;
  __shared__ float As[16][64];  // [k][m]
  __shared__ float Bs[16][64];  // [k][n]
  const int tid = threadIdx.x;
  // A staging: thread loads float4 along K; 4 threads cover 16 consecutive k of one row
  const int am  = tid >> 2;          // 0..63 (row within tile)
  const int akc = (tid & 3) << 2;    // 0,4,8,12 (k offset)
  // B staging: thread loads float4 along N
  const int bk = tid >> 4;           // 0..15
  const int bn = (tid & 15) << 2;    // 0..60
  // compute micro-tile
  const int tm = (tid >> 4) << 2;    // 0..60
  const int tn = (tid & 15) << 2;    // 0..60

  float acc[4][4] = {};

  for (int k0 = 0; k0 < K; k0 += 16) {
    float4 a4 = *(const float4*)&A[(m0 + am) * K + k0 + akc];
    float4 b4 = *(const float4*)&Bm[(k0 + bk) * N + n0 + bn];
    __syncthreads();
    As[akc + 0][am] = a4.x;
    As[akc + 1][am] = a4.y;
    As[akc + 2][am] = a4.z;
    As[akc + 3][am] = a4.w;
    *(float4*)&Bs[bk][bn] = b4;
    __syncthreads();
#pragma unroll
    for (int kk = 0; kk < 16; kk++) {
      float4 av = *(const float4*)&As[kk][tm];
      float4 bv = *(const float4*)&Bs[kk][tn];
      float a[4] = {av.x, av.y, av.z, av.w};
      float b[4] = {bv.x, bv.y, bv.z, bv.w};
#pragma unroll
      for (int i = 0; i < 4; i++)
#pragma unroll
        for (int j = 0; j < 4; j++) acc[i][j] = fmaf(a[i], b[j], acc[i][j]);
    }
  }

#pragma unroll
  for (int i = 0; i < 4; i++) {
#pragma unroll
    for (int j = 0; j < 4; j++) {
      float val = acc[i][j];
      if (bias) val += bias[n0 + tn + j];
      C[(m0 + tm + i) * N + n0 + tn + j] = val;
    }
  }
}

// Robust fast tanh: 1 - 2/(e^{2x}+1).  x->+inf => 1, x->-inf => -1.
__device__ __forceinline__ float tanh_fast(float x) {
  float e = __expf(2.0f * x);
  return 1.0f - 2.0f / (e + 1.0f);
}

// ---------------------------------------------------------------------------
// Fused additive-attention kernel: one block per (b,s).
//   q[t]   = sum_d tanh(Uh[b,s,d] + Wv[b,t,d]) * w[d]
//   beta   = softmax_t(q)
//   u[b,s,f] = sum_t beta[t] * v[b,t,f]
// 256 threads = 4 waves. Each wave handles t = wave, wave+4, ...
// Lane l covers d = 4l..4l+3 (float4), wave shuffle-reduce for the dot.
// ---------------------------------------------------------------------------
__global__ __launch_bounds__(256) void attn_fused_kernel(
    const float* __restrict__ Wv, const float* __restrict__ Uh,
    const float* __restrict__ w, const float* __restrict__ v,
    float* __restrict__ u) {
  const int bs = blockIdx.x;       // b*TH + s
  const int b  = bs >> 6;          // TH = 64
  const int wave = threadIdx.x >> 6;
  const int lane = threadIdx.x & 63;

  __shared__ float q_sm[TV];
  __shared__ float beta_sm[TV];

  const float4 uh4 = ((const float4*)(Uh + (size_t)bs * DD))[lane];
  const float4 w4  = ((const float4*)w)[lane];
  const float4* wv4 = (const float4*)(Wv + (size_t)b * TV * DD);

  for (int t = wave; t < TV; t += 4) {
    float4 wv = wv4[t * (DD / 4) + lane];
    float acc = tanh_fast(uh4.x + wv.x) * w4.x;
    acc = fmaf(tanh_fast(uh4.y + wv.y), w4.y, acc);
    acc = fmaf(tanh_fast(uh4.z + wv.z), w4.z, acc);
    acc = fmaf(tanh_fast(uh4.w + wv.w), w4.w, acc);
#pragma unroll
    for (int off = 32; off > 0; off >>= 1) acc += __shfl_xor(acc, off, 64);
    if (lane == 0) q_sm[t] = acc;
  }
  __syncthreads();

  if (wave == 0) {
    float q0 = q_sm[lane], q1 = q_sm[lane + 64];
    float m = fmaxf(q0, q1);
#pragma unroll
    for (int off = 32; off > 0; off >>= 1) m = fmaxf(m, __shfl_xor(m, off, 64));
    float e0 = __expf(q0 - m), e1 = __expf(q1 - m);
    float ss = e0 + e1;
#pragma unroll
    for (int off = 32; off > 0; off >>= 1) ss += __shfl_xor(ss, off, 64);
    float inv = 1.0f / ss;
    beta_sm[lane] = e0 * inv;
    beta_sm[lane + 64] = e1 * inv;
  }
  __syncthreads();

  // Context: u[bs, f] for f = tid and tid+256
  const float* vb = v + (size_t)b * TV * FF;
  const int f0 = threadIdx.x;
  float a0 = 0.0f, a1 = 0.0f;
  for (int t = 0; t < TV; t++) {
    float bt = beta_sm[t];
    a0 = fmaf(bt, vb[t * FF + f0], a0);
    a1 = fmaf(bt, vb[t * FF + f0 + 256], a1);
  }
  u[(size_t)bs * FF + f0] = a0;
  u[(size_t)bs * FF + f0 + 256] = a1;
}

extern "C" void kernel_launch(void* const* d_in, const int* in_sizes, int n_in,
                              void* d_out, int out_size, void* d_ws, size_t ws_size,
                              hipStream_t stream) {
  const float* v  = (const float*)d_in[0];  // [B, TV, F]
  const float* h  = (const float*)d_in[1];  // [B, TH, H]
  const float* W  = (const float*)d_in[2];  // [F, D]
  const float* U  = (const float*)d_in[3];  // [H, D]
  const float* bb = (const float*)d_in[4];  // [D]
  const float* w  = (const float*)d_in[5];  // [D, 1]
  float* u = (float*)d_out;                 // [B, TH, F]

  float* Wv = (float*)d_ws;                     // [B*TV, D] = 2048*256
  float* Uh = Wv + (size_t)BB * TV * DD;        // [B*TH, D] = 1024*256

  // Wv = v @ W      (M = B*TV = 2048, K = F = 512, N = D = 256)
  gemm_bias_kernel<<<dim3(DD / 64, (BB * TV) / 64), 256, 0, stream>>>(
      v, W, nullptr, Wv, FF, DD);
  // Uh = h @ U + b  (M = B*TH = 1024, K = H = 512, N = D = 256)
  gemm_bias_kernel<<<dim3(DD / 64, (BB * TH) / 64), 256, 0, stream>>>(
      h, U, bb, Uh, HH, DD);
  // Fused attention
  attn_fused_kernel<<<BB * TH, 256, 0, stream>>>(Wv, Uh, w, v, u);
}

// Round 2
// 133.567 us; speedup vs baseline: 1.1821x; 1.1821x over previous
//
#include <hip/hip_runtime.h>
#include <hip/hip_bf16.h>

// Problem constants: B=16, TV=128, TH=64, F=512, H=512, D=256
#define BB 16
#define TV 128
#define TH 64
#define FF 512
#define HH 512
#define DD 256

#define LOG2E2 2.8853900817779268f   // 2*log2(e): exp2(LOG2E2*x) = e^{2x}
#define LOG2E  1.4426950408889634f

__device__ __forceinline__ float fast_exp2(float x) {
#if __has_builtin(__builtin_amdgcn_exp2f)
  return __builtin_amdgcn_exp2f(x);
#else
  return __expf(x * 0.6931471805599453f);
#endif
}
__device__ __forceinline__ float fast_rcp(float x) {
#if __has_builtin(__builtin_amdgcn_rcpf)
  return __builtin_amdgcn_rcpf(x);
#else
  return 1.0f / x;
#endif
}

// ---------------------------------------------------------------------------
// Dual GEMM: blocks [0,256) : Wv2 = (v @ W) * LOG2E2            (M=2048)
//            blocks [256,384): Uh2 = (h @ U + b) * LOG2E2       (M=1024)
// K=512, N=256. Block: 256 thr = 4 waves; tile 64m x 32n (8n per wave).
// lane = m (outer product); A staged in LDS (At[32][65], conflict-free);
// B read via wave-uniform scalar loads (s_load path, off the LDS port).
// ---------------------------------------------------------------------------
__global__ __launch_bounds__(256) void dual_gemm_kernel(
    const float* __restrict__ v, const float* __restrict__ h,
    const float* __restrict__ W, const float* __restrict__ U,
    const float* __restrict__ bias,
    float* __restrict__ Wv2, float* __restrict__ Uh2) {
  __shared__ float At[32 * 65];

  const int bid = blockIdx.x;
  const float* A;
  const float* Bm;
  const float* bi;
  float* C;
  int mt, nt;
  if (bid < 256) {
    A = v; Bm = W; C = Wv2; bi = nullptr;
    mt = bid >> 3; nt = bid & 7;
  } else {
    const int b2 = bid - 256;
    A = h; Bm = U; C = Uh2; bi = bias;
    mt = b2 >> 3; nt = b2 & 7;
  }

  const int tid  = threadIdx.x;
  const int lane = tid & 63;                                   // = m offset
  const int wv   = __builtin_amdgcn_readfirstlane(tid >> 6);   // wave id (uniform)
  const int m0   = mt * 64;
  const int nb   = nt * 32 + wv * 8;                           // wave's n-block (uniform)

  // staging mapping: 8 rows/wave, 4 k-floats per thread, 2 row-passes
  const int r  = tid >> 3;          // 0..31
  const int kc = (tid & 7) << 2;    // 0,4,..,28

  float acc[8] = {};

  // initial stage of k-tile 0
  float4 p0 = *(const float4*)&A[(size_t)(m0 + r) * 512 + kc];
  float4 p1 = *(const float4*)&A[(size_t)(m0 + 32 + r) * 512 + kc];
#pragma unroll
  for (int i = 0; i < 4; i++) {
    At[(kc + i) * 65 + r]      = (&p0.x)[i];
    At[(kc + i) * 65 + 32 + r] = (&p1.x)[i];
  }
  __syncthreads();

  for (int k0 = 0; k0 < 512; k0 += 32) {
    // prefetch next k-tile into registers (overlaps compute)
    if (k0 + 32 < 512) {
      p0 = *(const float4*)&A[(size_t)(m0 + r) * 512 + k0 + 32 + kc];
      p1 = *(const float4*)&A[(size_t)(m0 + 32 + r) * 512 + k0 + 32 + kc];
    }
#pragma unroll
    for (int kk = 0; kk < 32; kk += 2) {
      float a0 = At[kk * 65 + lane];
      float a1 = At[(kk + 1) * 65 + lane];
#pragma unroll
      for (int j = 0; j < 8; j++) {
        acc[j] = fmaf(a0, Bm[(k0 + kk) * 256 + nb + j], acc[j]);      // s_load B
        acc[j] = fmaf(a1, Bm[(k0 + kk + 1) * 256 + nb + j], acc[j]);
      }
    }
    __syncthreads();
    if (k0 + 32 < 512) {
#pragma unroll
      for (int i = 0; i < 4; i++) {
        At[(kc + i) * 65 + r]      = (&p0.x)[i];
        At[(kc + i) * 65 + 32 + r] = (&p1.x)[i];
      }
    }
    __syncthreads();
  }

#pragma unroll
  for (int j = 0; j < 8; j++) {
    float val = acc[j];
    if (bi) val += bi[nb + j];
    C[(size_t)(m0 + lane) * 256 + nb + j] = val * LOG2E2;
  }
}

// ---------------------------------------------------------------------------
// Fused attention: grid 256 = (b in 16) x (sg in 16); 4 s-rows per block;
// 512 threads = 8 waves.
//   scores : q[s,t] = -2 * sum_d w[d] * rcp(exp2(Uh2[s,d]+Wv2[t,d]) + 1)
//            (softmax is shift-invariant; the dropped constant is sum_d w)
//   softmax over t (128), then u[s,f] = sum_t beta[s,t] * v[b,t,f]
// Wv2 streamed through LDS in 4 tiles of 32 t (register-prefetched).
// ---------------------------------------------------------------------------
#define WV_STRIDE 260   // 32 rows, pad for bank spread; 260%4==0 keeps b128 align

__global__ __launch_bounds__(512) void attn_fused_kernel(
    const float* __restrict__ Wv2, const float* __restrict__ Uh2,
    const float* __restrict__ wg, const float* __restrict__ v,
    float* __restrict__ u) {
  __shared__ float WvS[32 * WV_STRIDE];
  __shared__ float UhS[4 * WV_STRIDE];
  __shared__ float wS[WV_STRIDE];
  __shared__ float qS[4 * 128];
  __shared__ float bS[4 * 132];

  const int tid = threadIdx.x;
  const int b   = blockIdx.x >> 4;
  const int sg  = blockIdx.x & 15;

  // ---- stage Uh (4x256) and w (256) ----
  if (tid < 64) {
    const int su = tid >> 4, cu = tid & 15;
#pragma unroll
    for (int p = 0; p < 4; p++) {
      float4 t4 = *(const float4*)&Uh2[(size_t)((b * 64 + sg * 4 + su) * 256) + (cu + 16 * p) * 4];
      *(float4*)&UhS[su * WV_STRIDE + (cu + 16 * p) * 4] = t4;
    }
    *(float4*)&wS[tid * 4] = *(const float4*)&wg[tid * 4];
  }

  // ---- stage Wv tile 0 ----
  const int tw = tid >> 4, c = tid & 15;   // 32 rows x 16 float4-cols
  float4 pf[4];
#pragma unroll
  for (int p = 0; p < 4; p++)
    pf[p] = *(const float4*)&Wv2[(size_t)((b * 128 + tw) * 256) + (c + 16 * p) * 4];
#pragma unroll
  for (int p = 0; p < 4; p++)
    *(float4*)&WvS[tw * WV_STRIDE + (c + 16 * p) * 4] = pf[p];
  __syncthreads();

  // ---- scores: thread = (s, t_local, d-quarter) ----
  const int s  = tid >> 7;          // 0..3
  const int tl = (tid >> 2) & 31;   // 0..31
  const int dq = tid & 3;           // 0..3 (64 d each)

  for (int tile = 0; tile < 4; tile++) {
    if (tile < 3) {
#pragma unroll
      for (int p = 0; p < 4; p++)
        pf[p] = *(const float4*)&Wv2[(size_t)((b * 128 + (tile + 1) * 32 + tw) * 256) + (c + 16 * p) * 4];
    }
    float acc = 0.0f;
    const float4* wvrow = (const float4*)&WvS[tl * WV_STRIDE] + dq * 16;
    const float4* uhrow = (const float4*)&UhS[s * WV_STRIDE] + dq * 16;
    const float4* wrow  = (const float4*)&wS[0] + dq * 16;
#pragma unroll
    for (int j = 0; j < 16; j++) {
      float4 a  = wvrow[j];
      float4 uh = uhrow[j];
      float4 ww = wrow[j];
      acc = fmaf(ww.x, fast_rcp(fast_exp2(a.x + uh.x) + 1.0f), acc);
      acc = fmaf(ww.y, fast_rcp(fast_exp2(a.y + uh.y) + 1.0f), acc);
      acc = fmaf(ww.z, fast_rcp(fast_exp2(a.z + uh.z) + 1.0f), acc);
      acc = fmaf(ww.w, fast_rcp(fast_exp2(a.w + uh.w) + 1.0f), acc);
    }
    acc += __shfl_xor(acc, 1, 64);
    acc += __shfl_xor(acc, 2, 64);
    if (dq == 0) qS[s * 128 + tile * 32 + tl] = -2.0f * acc;
    __syncthreads();
    if (tile < 3) {
#pragma unroll
      for (int p = 0; p < 4; p++)
        *(float4*)&WvS[tw * WV_STRIDE + (c + 16 * p) * 4] = pf[p];
    }
    __syncthreads();
  }

  // ---- softmax over t (waves 0..3, one per s-row) ----
  const int wvid = tid >> 6, lane = tid & 63;
  if (wvid < 4) {
    float q0 = qS[wvid * 128 + lane];
    float q1 = qS[wvid * 128 + 64 + lane];
    float m = fmaxf(q0, q1);
#pragma unroll
    for (int off = 32; off > 0; off >>= 1) m = fmaxf(m, __shfl_xor(m, off, 64));
    float e0 = fast_exp2((q0 - m) * LOG2E);
    float e1 = fast_exp2((q1 - m) * LOG2E);
    float ssum = e0 + e1;
#pragma unroll
    for (int off = 32; off > 0; off >>= 1) ssum += __shfl_xor(ssum, off, 64);
    float inv = fast_rcp(ssum);
    bS[wvid * 132 + lane]      = e0 * inv;
    bS[wvid * 132 + 64 + lane] = e1 * inv;
  }
  __syncthreads();

  // ---- context: thread = f (512); each v read feeds 4 s-rows ----
  const float* vb = v + (size_t)b * TV * FF;
  const int f = tid;
  float a0 = 0.f, a1 = 0.f, a2 = 0.f, a3 = 0.f;
#pragma unroll 4
  for (int tg = 0; tg < 128; tg += 4) {
    float4 b0 = *(const float4*)&bS[0 * 132 + tg];
    float4 b1 = *(const float4*)&bS[1 * 132 + tg];
    float4 b2 = *(const float4*)&bS[2 * 132 + tg];
    float4 b3 = *(const float4*)&bS[3 * 132 + tg];
    float v0 = vb[(tg + 0) * 512 + f];
    float v1 = vb[(tg + 1) * 512 + f];
    float v2 = vb[(tg + 2) * 512 + f];
    float v3 = vb[(tg + 3) * 512 + f];
    a0 = fmaf(b0.x, v0, a0); a0 = fmaf(b0.y, v1, a0); a0 = fmaf(b0.z, v2, a0); a0 = fmaf(b0.w, v3, a0);
    a1 = fmaf(b1.x, v0, a1); a1 = fmaf(b1.y, v1, a1); a1 = fmaf(b1.z, v2, a1); a1 = fmaf(b1.w, v3, a1);
    a2 = fmaf(b2.x, v0, a2); a2 = fmaf(b2.y, v1, a2); a2 = fmaf(b2.z, v2, a2); a2 = fmaf(b2.w, v3, a2);
    a3 = fmaf(b3.x, v0, a3); a3 = fmaf(b3.y, v1, a3); a3 = fmaf(b3.z, v2, a3); a3 = fmaf(b3.w, v3, a3);
  }
  float* urow = u + (size_t)(b * 64 + sg * 4) * 512;
  urow[0 * 512 + f] = a0;
  urow[1 * 512 + f] = a1;
  urow[2 * 512 + f] = a2;
  urow[3 * 512 + f] = a3;
}

extern "C" void kernel_launch(void* const* d_in, const int* in_sizes, int n_in,
                              void* d_out, int out_size, void* d_ws, size_t ws_size,
                              hipStream_t stream) {
  const float* v  = (const float*)d_in[0];  // [16,128,512]
  const float* h  = (const float*)d_in[1];  // [16,64,512]
  const float* W  = (const float*)d_in[2];  // [512,256]
  const float* U  = (const float*)d_in[3];  // [512,256]
  const float* bb = (const float*)d_in[4];  // [256]
  const float* w  = (const float*)d_in[5];  // [256,1]
  float* u = (float*)d_out;                 // [16,64,512]

  float* Wv2 = (float*)d_ws;                      // [2048,256] prescaled
  float* Uh2 = Wv2 + (size_t)2048 * 256;          // [1024,256] prescaled (+bias)

  dual_gemm_kernel<<<384, 256, 0, stream>>>(v, h, W, U, bb, Wv2, Uh2);
  attn_fused_kernel<<<256, 512, 0, stream>>>(Wv2, Uh2, w, v, u);
}

// Round 3
// 128.729 us; speedup vs baseline: 1.2266x; 1.0376x over previous
//
#include <hip/hip_runtime.h>
#include <hip/hip_bf16.h>

// Problem constants: B=16, TV=128, TH=64, F=512, H=512, D=256
#define BB 16
#define TV 128
#define TH 64
#define FF 512
#define HH 512
#define DD 256

#define LOG2E2 2.8853900817779268f   // 2*log2(e): exp2(LOG2E2*x) = e^{2x}
#define LOG2E  1.4426950408889634f

__device__ __forceinline__ float fast_exp2(float x) {
#if __has_builtin(__builtin_amdgcn_exp2f)
  return __builtin_amdgcn_exp2f(x);
#else
  return __expf(x * 0.6931471805599453f);
#endif
}
__device__ __forceinline__ float fast_rcp(float x) {
#if __has_builtin(__builtin_amdgcn_rcpf)
  return __builtin_amdgcn_rcpf(x);
#else
  return 1.0f / x;
#endif
}

// ---------------------------------------------------------------------------
// Dual GEMM, fp32, double-buffered LDS for A and B.
//   blocks [0,128) : Wv2 = (v @ W) * LOG2E2          (M=2048, 32 m-tiles x 4 n)
//   blocks [128,192): Uh2 = (h @ U + b) * LOG2E2     (M=1024, 16 m-tiles x 4 n)
// Tile 64m x 64n, BK=16, 256 thr = 4 waves. Wave w: 64m x 16n, lane = m.
//   A in LDS As[64][17]  -> per-kk b32 read, stride 17 => 2-way/bank (free)
//   B in LDS Bs[16][68]  -> wave-uniform b128 broadcasts (free)
// Per block: 2M MACs -> 16.4K cyc FMA-bound.
// ---------------------------------------------------------------------------
__global__ __launch_bounds__(256) void dual_gemm_kernel(
    const float* __restrict__ v, const float* __restrict__ h,
    const float* __restrict__ W, const float* __restrict__ U,
    const float* __restrict__ bias,
    float* __restrict__ Wv2, float* __restrict__ Uh2) {
  __shared__ float As[2][64 * 17];
  __shared__ float Bs[2][16 * 68];

  const int bid = blockIdx.x;
  const float* A;
  const float* Bm;
  const float* bi;
  float* C;
  int mt, nt;
  if (bid < 128) {
    A = v; Bm = W; C = Wv2; bi = nullptr;
    mt = bid >> 2; nt = bid & 3;
  } else {
    const int b2 = bid - 128;
    A = h; Bm = U; C = Uh2; bi = bias;
    mt = b2 >> 2; nt = b2 & 3;
  }

  const int tid  = threadIdx.x;
  const int lane = tid & 63;                                  // m within tile
  const int wv   = __builtin_amdgcn_readfirstlane(tid >> 6);  // wave id 0..3
  const int m0   = mt * 64;
  const int n0   = nt * 64;
  const int nb   = wv * 16;                                   // wave n-offset in tile

  // staging mapping
  const int ar = tid >> 2;            // A row 0..63
  const int ak = (tid & 3) << 2;      // A k-quad 0,4,8,12
  const int bk = tid >> 4;            // B k-row 0..15
  const int bn = (tid & 15) << 2;     // B n-col 0,4,..,60

  const float* Aptr = A + (size_t)(m0 + ar) * 512 + ak;
  const float* Bptr = Bm + (size_t)bk * 256 + n0 + bn;

  float acc[16] = {};

  // tile 0
  float4 pa = *(const float4*)Aptr;
  float4 pb = *(const float4*)Bptr;
#pragma unroll
  for (int i = 0; i < 4; i++) As[0][ar * 17 + ak + i] = (&pa.x)[i];
  *(float4*)&Bs[0][bk * 68 + bn] = pb;
  __syncthreads();

  for (int t = 0; t < 32; t++) {
    const int cur = t & 1;
    if (t + 1 < 32) {
      pa = *(const float4*)(Aptr + (t + 1) * 16);
      pb = *(const float4*)(Bptr + (size_t)(t + 1) * 16 * 256);
    }
#pragma unroll
    for (int kk = 0; kk < 16; kk++) {
      float a = As[cur][lane * 17 + kk];
      const float4* brow = (const float4*)&Bs[cur][kk * 68 + nb];
      float4 b0 = brow[0], b1 = brow[1], b2 = brow[2], b3 = brow[3];
      acc[0]  = fmaf(a, b0.x, acc[0]);  acc[1]  = fmaf(a, b0.y, acc[1]);
      acc[2]  = fmaf(a, b0.z, acc[2]);  acc[3]  = fmaf(a, b0.w, acc[3]);
      acc[4]  = fmaf(a, b1.x, acc[4]);  acc[5]  = fmaf(a, b1.y, acc[5]);
      acc[6]  = fmaf(a, b1.z, acc[6]);  acc[7]  = fmaf(a, b1.w, acc[7]);
      acc[8]  = fmaf(a, b2.x, acc[8]);  acc[9]  = fmaf(a, b2.y, acc[9]);
      acc[10] = fmaf(a, b2.z, acc[10]); acc[11] = fmaf(a, b2.w, acc[11]);
      acc[12] = fmaf(a, b3.x, acc[12]); acc[13] = fmaf(a, b3.y, acc[13]);
      acc[14] = fmaf(a, b3.z, acc[14]); acc[15] = fmaf(a, b3.w, acc[15]);
    }
    if (t + 1 < 32) {
      const int nxt = cur ^ 1;
#pragma unroll
      for (int i = 0; i < 4; i++) As[nxt][ar * 17 + ak + i] = (&pa.x)[i];
      *(float4*)&Bs[nxt][bk * 68 + bn] = pb;
    }
    __syncthreads();
  }

  // epilogue: bias + prescale by 2*log2(e)
  float bvals[16];
#pragma unroll
  for (int j = 0; j < 16; j++) bvals[j] = bi ? bi[n0 + nb + j] : 0.0f;
  float* Crow = C + (size_t)(m0 + lane) * 256 + n0 + nb;
#pragma unroll
  for (int j4 = 0; j4 < 4; j4++) {
    float4 o;
    o.x = (acc[j4 * 4 + 0] + bvals[j4 * 4 + 0]) * LOG2E2;
    o.y = (acc[j4 * 4 + 1] + bvals[j4 * 4 + 1]) * LOG2E2;
    o.z = (acc[j4 * 4 + 2] + bvals[j4 * 4 + 2]) * LOG2E2;
    o.w = (acc[j4 * 4 + 3] + bvals[j4 * 4 + 3]) * LOG2E2;
    *(float4*)&Crow[j4 * 4] = o;
  }
}

// ---------------------------------------------------------------------------
// Fused attention. Grid 256 = (b:16) x (sg:16), 4 s-rows/block, 512 thr.
// Score phase: thread = (s, t); full 256-d dot in one thread.
//   q[s,t] = -2 * sum_d w[d] * rcp(exp2(Uh2[s,d] + Wv2[t,d]) + 1)
//   Wv2 rows read straight from global (L2-resident); Uh2/w from LDS
//   broadcasts (wave-uniform). q stays in-register.
// Softmax over t: wave shuffle-reduce + 2-wave combine via LDS.
// Context: thread = f; coalesced v reads, broadcast beta reads.
// ---------------------------------------------------------------------------
__global__ __launch_bounds__(512) void attn_fused_kernel(
    const float* __restrict__ Wv2, const float* __restrict__ Uh2,
    const float* __restrict__ wg, const float* __restrict__ v,
    float* __restrict__ u) {
  __shared__ float UhS[4 * 256];
  __shared__ float wS[256];
  __shared__ float bS[4 * 128];
  __shared__ float mW[8];
  __shared__ float sW[8];

  const int tid = threadIdx.x;
  const int b   = blockIdx.x >> 4;
  const int sg  = blockIdx.x & 15;
  const int s0  = sg * 4;

  // ---- stage Uh (4x256) and w (256) ----
  if (tid < 256) {
    const int row = tid >> 6, q4 = (tid & 63) << 2;
    *(float4*)&UhS[row * 256 + q4] =
        *(const float4*)&Uh2[(size_t)(b * 64 + s0 + row) * 256 + q4];
  } else if (tid < 320) {
    const int q4 = (tid - 256) << 2;
    *(float4*)&wS[q4] = *(const float4*)&wg[q4];
  }
  __syncthreads();

  // ---- scores ----
  const int s_l = tid >> 7;     // 0..3  (wave-uniform: wave = tid>>6)
  const int t   = tid & 127;    // 0..127

  const float4* wvrow = (const float4*)(Wv2 + (size_t)(b * 128 + t) * 256);
  const float4* uhrow = (const float4*)&UhS[s_l * 256];
  const float4* wrow  = (const float4*)&wS[0];

  float acc = 0.0f;
#pragma unroll 8
  for (int j = 0; j < 64; j++) {
    float4 a  = wvrow[j];
    float4 uh = uhrow[j];
    float4 ww = wrow[j];
    acc = fmaf(ww.x, fast_rcp(fast_exp2(a.x + uh.x) + 1.0f), acc);
    acc = fmaf(ww.y, fast_rcp(fast_exp2(a.y + uh.y) + 1.0f), acc);
    acc = fmaf(ww.z, fast_rcp(fast_exp2(a.z + uh.z) + 1.0f), acc);
    acc = fmaf(ww.w, fast_rcp(fast_exp2(a.w + uh.w) + 1.0f), acc);
  }
  float q = -2.0f * acc;

  // ---- softmax over t (each s spans 2 waves) ----
  const int wvid = tid >> 6;
  const int lane = tid & 63;
  float m = q;
#pragma unroll
  for (int off = 32; off > 0; off >>= 1) m = fmaxf(m, __shfl_xor(m, off, 64));
  if (lane == 0) mW[wvid] = m;
  __syncthreads();
  m = fmaxf(mW[wvid], mW[wvid ^ 1]);
  float e = fast_exp2((q - m) * LOG2E);
  float ssum = e;
#pragma unroll
  for (int off = 32; off > 0; off >>= 1) ssum += __shfl_xor(ssum, off, 64);
  if (lane == 0) sW[wvid] = ssum;
  __syncthreads();
  float inv = fast_rcp(sW[wvid] + sW[wvid ^ 1]);
  bS[s_l * 128 + t] = e * inv;
  __syncthreads();

  // ---- context: thread = f; each v read feeds 4 s-rows ----
  const float* vb = v + (size_t)b * TV * FF;
  const int f = tid;
  float a0 = 0.f, a1 = 0.f, a2 = 0.f, a3 = 0.f;
#pragma unroll 4
  for (int tg = 0; tg < 128; tg += 4) {
    float4 b0 = *(const float4*)&bS[0 * 128 + tg];
    float4 b1 = *(const float4*)&bS[1 * 128 + tg];
    float4 b2 = *(const float4*)&bS[2 * 128 + tg];
    float4 b3 = *(const float4*)&bS[3 * 128 + tg];
    float v0 = vb[(tg + 0) * 512 + f];
    float v1 = vb[(tg + 1) * 512 + f];
    float v2 = vb[(tg + 2) * 512 + f];
    float v3 = vb[(tg + 3) * 512 + f];
    a0 = fmaf(b0.x, v0, a0); a0 = fmaf(b0.y, v1, a0); a0 = fmaf(b0.z, v2, a0); a0 = fmaf(b0.w, v3, a0);
    a1 = fmaf(b1.x, v0, a1); a1 = fmaf(b1.y, v1, a1); a1 = fmaf(b1.z, v2, a1); a1 = fmaf(b1.w, v3, a1);
    a2 = fmaf(b2.x, v0, a2); a2 = fmaf(b2.y, v1, a2); a2 = fmaf(b2.z, v2, a2); a2 = fmaf(b2.w, v3, a2);
    a3 = fmaf(b3.x, v0, a3); a3 = fmaf(b3.y, v1, a3); a3 = fmaf(b3.z, v2, a3); a3 = fmaf(b3.w, v3, a3);
  }
  float* urow = u + (size_t)(b * 64 + s0) * 512;
  urow[0 * 512 + f] = a0;
  urow[1 * 512 + f] = a1;
  urow[2 * 512 + f] = a2;
  urow[3 * 512 + f] = a3;
}

extern "C" void kernel_launch(void* const* d_in, const int* in_sizes, int n_in,
                              void* d_out, int out_size, void* d_ws, size_t ws_size,
                              hipStream_t stream) {
  const float* v  = (const float*)d_in[0];  // [16,128,512]
  const float* h  = (const float*)d_in[1];  // [16,64,512]
  const float* W  = (const float*)d_in[2];  // [512,256]
  const float* U  = (const float*)d_in[3];  // [512,256]
  const float* bb = (const float*)d_in[4];  // [256]
  const float* w  = (const float*)d_in[5];  // [256,1]
  float* u = (float*)d_out;                 // [16,64,512]

  float* Wv2 = (float*)d_ws;                      // [2048,256] prescaled
  float* Uh2 = Wv2 + (size_t)2048 * 256;          // [1024,256] prescaled (+bias)

  dual_gemm_kernel<<<192, 256, 0, stream>>>(v, h, W, U, bb, Wv2, Uh2);
  attn_fused_kernel<<<256, 512, 0, stream>>>(Wv2, Uh2, w, v, u);
}

// Round 4
// 100.691 us; speedup vs baseline: 1.5681x; 1.2785x over previous
//
#include <hip/hip_runtime.h>
#include <hip/hip_bf16.h>

// Problem constants: B=16, TV=128, TH=64, F=512, H=512, D=256
#define BB 16
#define TV 128
#define TH 64
#define FF 512
#define HH 512
#define DD 256

#define LOG2E2 2.8853900817779268f   // 2*log2(e): exp2(LOG2E2*x) = e^{2x}

typedef __attribute__((ext_vector_type(8))) short bf16x8;   // 8 bf16 = 4 VGPRs
typedef __attribute__((ext_vector_type(4))) float f32x4;

__device__ __forceinline__ float fast_exp2(float x) {
#if __has_builtin(__builtin_amdgcn_exp2f)
  return __builtin_amdgcn_exp2f(x);
#else
  return __expf(x * 0.6931471805599453f);
#endif
}
__device__ __forceinline__ float fast_rcp(float x) {
#if __has_builtin(__builtin_amdgcn_rcpf)
  return __builtin_amdgcn_rcpf(x);
#else
  return 1.0f / x;
#endif
}
__device__ __forceinline__ unsigned short f2bf(float x) {  // RNE fp32->bf16
  union { float f; unsigned u; } a; a.f = x;
  unsigned r = a.u + 0x7fffu + ((a.u >> 16) & 1u);
  return (unsigned short)(r >> 16);
}

// ---------------------------------------------------------------------------
// Convert kernel: v,h -> bf16 (row-major); W,U -> bf16 TRANSPOSED ([n][k]).
// Exact grid: 1792 blocks * 256 thr = 458752 tasks.
//   tasks [0, 262144):        v float4 -> 4 bf16
//   tasks [262144, 393216):   h float4 -> 4 bf16
//   tasks [393216, 425984):   W transpose (n = t&255, k4 = t>>8)
//   tasks [425984, 458752):   U transpose
// ---------------------------------------------------------------------------
#define NT_V 262144
#define NT_H 131072
#define NT_W 32768
__global__ __launch_bounds__(256) void convert_kernel(
    const float* __restrict__ v, const float* __restrict__ h,
    const float* __restrict__ W, const float* __restrict__ U,
    unsigned short* __restrict__ vb, unsigned short* __restrict__ hb,
    unsigned short* __restrict__ WT, unsigned short* __restrict__ UT) {
  int task = blockIdx.x * 256 + threadIdx.x;
  if (task < NT_V) {
    float4 x = ((const float4*)v)[task];
    ushort4 o = make_ushort4(f2bf(x.x), f2bf(x.y), f2bf(x.z), f2bf(x.w));
    *(ushort4*)&vb[(size_t)task * 4] = o;
  } else if (task < NT_V + NT_H) {
    int t2 = task - NT_V;
    float4 x = ((const float4*)h)[t2];
    ushort4 o = make_ushort4(f2bf(x.x), f2bf(x.y), f2bf(x.z), f2bf(x.w));
    *(ushort4*)&hb[(size_t)t2 * 4] = o;
  } else {
    int t2 = task - NT_V - NT_H;
    const float* S;
    unsigned short* Dt;
    if (t2 < NT_W) { S = W; Dt = WT; } else { S = U; Dt = UT; t2 -= NT_W; }
    int n = t2 & 255, k4 = t2 >> 8;           // k4 in [0,128)
    float a0 = S[(k4 * 4 + 0) * 256 + n];     // coalesced: consecutive n per lane
    float a1 = S[(k4 * 4 + 1) * 256 + n];
    float a2 = S[(k4 * 4 + 2) * 256 + n];
    float a3 = S[(k4 * 4 + 3) * 256 + n];
    ushort4 o = make_ushort4(f2bf(a0), f2bf(a1), f2bf(a2), f2bf(a3));
    *(ushort4*)&Dt[(size_t)n * 512 + k4 * 4] = o;
  }
}

// ---------------------------------------------------------------------------
// MFMA GEMM, no LDS, no barriers. 384 blocks * 128 thr (2 waves).
//   blocks [0,256):   Wv2 = (v @ W) * LOG2E2      M=2048: mt=bid>>3, nt=bid&7
//   blocks [256,384): Uh2 = (h @ U + b) * LOG2E2  M=1024
// Wave tile: 32m x 32n x 512k via 2x2 of mfma_f32_16x16x32_bf16.
// A-frag: lane -> A[m0 + (l&15)][k0 + (l>>4)*8 ..+7]   (16 B contiguous)
// B-frag: lane -> BT[n0 + (l&15)][k0 + (l>>4)*8 ..+7]  (B^T rows, 16 B)
// C/D:    col = l&15, row = (l>>4)*4 + reg             (m89-verified)
// ---------------------------------------------------------------------------
__global__ __launch_bounds__(128) void mfma_gemm_kernel(
    const unsigned short* __restrict__ Av, const unsigned short* __restrict__ Ah,
    const unsigned short* __restrict__ WT, const unsigned short* __restrict__ UT,
    const float* __restrict__ bias, float* __restrict__ Wv2,
    float* __restrict__ Uh2) {
  const int bid = blockIdx.x;
  const unsigned short* A;
  const unsigned short* BT;
  const float* bi;
  float* C;
  int mt, nt;
  if (bid < 256) {
    A = Av; BT = WT; C = Wv2; bi = nullptr;
    mt = bid >> 3; nt = bid & 7;
  } else {
    const int b2 = bid - 256;
    A = Ah; BT = UT; C = Uh2; bi = bias;
    mt = b2 >> 3; nt = b2 & 7;
  }
  const int wv   = threadIdx.x >> 6;   // 0..1
  const int lane = threadIdx.x & 63;
  const int m0   = mt * 64 + wv * 32;
  const int n0   = nt * 32;
  const int r16  = lane & 15;
  const int quad = lane >> 4;

  const unsigned short* a0p = A + (size_t)(m0 + r16) * 512 + quad * 8;
  const unsigned short* a1p = a0p + 16 * 512;
  const unsigned short* b0p = BT + (size_t)(n0 + r16) * 512 + quad * 8;
  const unsigned short* b1p = b0p + 16 * 512;

  f32x4 acc00 = {0.f, 0.f, 0.f, 0.f};
  f32x4 acc01 = {0.f, 0.f, 0.f, 0.f};
  f32x4 acc10 = {0.f, 0.f, 0.f, 0.f};
  f32x4 acc11 = {0.f, 0.f, 0.f, 0.f};

#pragma unroll
  for (int kc = 0; kc < 16; kc++) {
    bf16x8 a0 = *(const bf16x8*)(a0p + kc * 32);
    bf16x8 a1 = *(const bf16x8*)(a1p + kc * 32);
    bf16x8 b0 = *(const bf16x8*)(b0p + kc * 32);
    bf16x8 b1 = *(const bf16x8*)(b1p + kc * 32);
    acc00 = __builtin_amdgcn_mfma_f32_16x16x32_bf16(a0, b0, acc00, 0, 0, 0);
    acc01 = __builtin_amdgcn_mfma_f32_16x16x32_bf16(a0, b1, acc01, 0, 0, 0);
    acc10 = __builtin_amdgcn_mfma_f32_16x16x32_bf16(a1, b0, acc10, 0, 0, 0);
    acc11 = __builtin_amdgcn_mfma_f32_16x16x32_bf16(a1, b1, acc11, 0, 0, 0);
  }

  const float bj0 = bi ? bi[n0 + r16] : 0.0f;
  const float bj1 = bi ? bi[n0 + 16 + r16] : 0.0f;
#pragma unroll
  for (int r = 0; r < 4; r++) {
    const int row0 = m0 + quad * 4 + r;
    C[(size_t)row0 * 256 + n0 + r16]            = (acc00[r] + bj0) * LOG2E2;
    C[(size_t)row0 * 256 + n0 + 16 + r16]       = (acc01[r] + bj1) * LOG2E2;
    C[(size_t)(row0 + 16) * 256 + n0 + r16]     = (acc10[r] + bj0) * LOG2E2;
    C[(size_t)(row0 + 16) * 256 + n0 + 16 + r16] = (acc11[r] + bj1) * LOG2E2;
  }
}

// ---------------------------------------------------------------------------
// Fused attention. 256 blocks = (b:16)x(sg:16), 4 s-rows/block, 1024 thr
// (16 waves = 4 waves/SIMD at 1 block/CU).
// Score: thread = (s:4, t:128, dh:2), each does 128 d; partials -> LDS.
//   q[s,t] = -2*sum_d w[d]*sigma(...) with softmax-invariant constant dropped;
//   computed directly in log2-domain: Q = (p0+p1) * (-LOG2E2) ... wait, note
//   Wv2/Uh2 are prescaled by 2*log2(e), so exp2(Uh2+Wv2) = e^{2(uh+wv+b)}.
// Softmax over t by threads < 512 (2 waves per s-row), exact v2 logic.
// Context: thread = (f:512, sh:2), 2 s-rows per thread, coalesced v reads.
// ---------------------------------------------------------------------------
__global__ __launch_bounds__(1024) void attn_fused_kernel(
    const float* __restrict__ Wv2, const float* __restrict__ Uh2,
    const float* __restrict__ wg, const float* __restrict__ v,
    float* __restrict__ u) {
  __shared__ float UhS[4 * 256];
  __shared__ float wS[256];
  __shared__ float pS[1024];
  __shared__ float bS[4 * 128];
  __shared__ float mW[8];
  __shared__ float sW[8];

  const int tid = threadIdx.x;
  const int b   = blockIdx.x >> 4;
  const int sg  = blockIdx.x & 15;
  const int s0  = sg * 4;

  // ---- stage Uh (4x256) and w (256) ----
  if (tid < 256) {
    const int row = tid >> 6, q4 = (tid & 63) << 2;
    *(float4*)&UhS[row * 256 + q4] =
        *(const float4*)&Uh2[(size_t)(b * 64 + s0 + row) * 256 + q4];
  } else if (tid < 320) {
    const int q4 = (tid - 256) << 2;
    *(float4*)&wS[q4] = *(const float4*)&wg[q4];
  }
  __syncthreads();

  // ---- scores: thread = (s, dh, t); 128 d each ----
  {
    const int t    = tid & 127;
    const int dh   = (tid >> 7) & 1;
    const int s_sc = tid >> 8;
    const float4* wvrow = (const float4*)(Wv2 + (size_t)(b * 128 + t) * 256) + dh * 32;
    const float4* uhrow = (const float4*)&UhS[s_sc * 256] + dh * 32;
    const float4* wrow  = (const float4*)&wS[0] + dh * 32;
    float acc = 0.0f;
#pragma unroll 8
    for (int j = 0; j < 32; j++) {
      float4 a  = wvrow[j];
      float4 uh = uhrow[j];
      float4 ww = wrow[j];
      acc = fmaf(ww.x, fast_rcp(fast_exp2(a.x + uh.x) + 1.0f), acc);
      acc = fmaf(ww.y, fast_rcp(fast_exp2(a.y + uh.y) + 1.0f), acc);
      acc = fmaf(ww.z, fast_rcp(fast_exp2(a.z + uh.z) + 1.0f), acc);
      acc = fmaf(ww.w, fast_rcp(fast_exp2(a.w + uh.w) + 1.0f), acc);
    }
    pS[tid] = acc;
  }
  __syncthreads();

  // ---- softmax over t: threads < 512, s_l = tid>>7, t = tid&127 ----
  float qv = 0.0f, ev = 0.0f;
  const int wvid = tid >> 6, lane = tid & 63;
  if (tid < 512) {
    const int s_l = tid >> 7, t = tid & 127;
    // log2-domain score: q_nat*log2(e) = -LOG2E2 * (p0 + p1)
    qv = (pS[s_l * 256 + t] + pS[s_l * 256 + 128 + t]) * (-LOG2E2);
    float m = qv;
#pragma unroll
    for (int off = 32; off > 0; off >>= 1) m = fmaxf(m, __shfl_xor(m, off, 64));
    if (lane == 0) mW[wvid] = m;
  }
  __syncthreads();
  if (tid < 512) {
    float m = fmaxf(mW[wvid], mW[wvid ^ 1]);
    ev = fast_exp2(qv - m);
    float ssum = ev;
#pragma unroll
    for (int off = 32; off > 0; off >>= 1) ssum += __shfl_xor(ssum, off, 64);
    if (lane == 0) sW[wvid] = ssum;
  }
  __syncthreads();
  if (tid < 512) {
    const int s_l = tid >> 7, t = tid & 127;
    bS[s_l * 128 + t] = ev * fast_rcp(sW[wvid] + sW[wvid ^ 1]);
  }
  __syncthreads();

  // ---- context: thread = (f:512, sh:2); 2 s-rows each ----
  const float* vb2 = v + (size_t)b * TV * FF;
  const int f  = tid & 511;
  const int sh = tid >> 9;
  float a0 = 0.f, a1 = 0.f;
#pragma unroll 4
  for (int tg = 0; tg < 128; tg += 4) {
    float4 b0 = *(const float4*)&bS[(sh * 2 + 0) * 128 + tg];
    float4 b1 = *(const float4*)&bS[(sh * 2 + 1) * 128 + tg];
    float v0 = vb2[(tg + 0) * 512 + f];
    float v1 = vb2[(tg + 1) * 512 + f];
    float v2 = vb2[(tg + 2) * 512 + f];
    float v3 = vb2[(tg + 3) * 512 + f];
    a0 = fmaf(b0.x, v0, a0); a0 = fmaf(b0.y, v1, a0);
    a0 = fmaf(b0.z, v2, a0); a0 = fmaf(b0.w, v3, a0);
    a1 = fmaf(b1.x, v0, a1); a1 = fmaf(b1.y, v1, a1);
    a1 = fmaf(b1.z, v2, a1); a1 = fmaf(b1.w, v3, a1);
  }
  float* urow = u + (size_t)(b * 64 + s0 + sh * 2) * 512;
  urow[0 * 512 + f] = a0;
  urow[1 * 512 + f] = a1;
}

extern "C" void kernel_launch(void* const* d_in, const int* in_sizes, int n_in,
                              void* d_out, int out_size, void* d_ws, size_t ws_size,
                              hipStream_t stream) {
  const float* v  = (const float*)d_in[0];  // [16,128,512]
  const float* h  = (const float*)d_in[1];  // [16,64,512]
  const float* W  = (const float*)d_in[2];  // [512,256]
  const float* U  = (const float*)d_in[3];  // [512,256]
  const float* bb = (const float*)d_in[4];  // [256]
  const float* w  = (const float*)d_in[5];  // [256,1]
  float* u = (float*)d_out;                 // [16,64,512]

  float* Wv2 = (float*)d_ws;                       // [2048,256] f32 prescaled
  float* Uh2 = Wv2 + (size_t)2048 * 256;           // [1024,256] f32 prescaled
  unsigned short* vb16 = (unsigned short*)(Uh2 + (size_t)1024 * 256);
  unsigned short* hb16 = vb16 + (size_t)2048 * 512;  // bf16 copies
  unsigned short* WT   = hb16 + (size_t)1024 * 512;  // [256][512] bf16 (W^T)
  unsigned short* UT   = WT + (size_t)256 * 512;     // [256][512] bf16 (U^T)

  convert_kernel<<<1792, 256, 0, stream>>>(v, h, W, U, vb16, hb16, WT, UT);
  mfma_gemm_kernel<<<384, 128, 0, stream>>>(vb16, hb16, WT, UT, bb, Wv2, Uh2);
  attn_fused_kernel<<<256, 1024, 0, stream>>>(Wv2, Uh2, w, v, u);
}

// Round 5
// 92.870 us; speedup vs baseline: 1.7002x; 1.0842x over previous
//
#include <hip/hip_runtime.h>
#include <hip/hip_bf16.h>

// Problem constants: B=16, TV=128, TH=64, F=512, H=512, D=256
#define BB 16
#define TV 128
#define TH 64
#define FF 512
#define HH 512
#define DD 256

#define LOG2E2 2.8853900817779268f   // 2*log2(e): exp2(LOG2E2*x) = e^{2x}

typedef __attribute__((ext_vector_type(8))) short bf16x8;   // 8 bf16 = 4 VGPRs
typedef __attribute__((ext_vector_type(4))) float f32x4;

__device__ __forceinline__ float fast_exp2(float x) {
#if __has_builtin(__builtin_amdgcn_exp2f)
  return __builtin_amdgcn_exp2f(x);
#else
  return __expf(x * 0.6931471805599453f);
#endif
}
__device__ __forceinline__ float fast_rcp(float x) {
#if __has_builtin(__builtin_amdgcn_rcpf)
  return __builtin_amdgcn_rcpf(x);
#else
  return 1.0f / x;
#endif
}
__device__ __forceinline__ unsigned short f2bf(float x) {  // RNE fp32->bf16
  union { float f; unsigned u; } a; a.f = x;
  unsigned r = a.u + 0x7fffu + ((a.u >> 16) & 1u);
  return (unsigned short)(r >> 16);
}

// ---------------------------------------------------------------------------
// Convert kernel: v,h -> bf16 (row-major); W,U -> bf16 TRANSPOSED ([n][k]).
// ---------------------------------------------------------------------------
#define NT_V 262144
#define NT_H 131072
#define NT_W 32768
__global__ __launch_bounds__(256) void convert_kernel(
    const float* __restrict__ v, const float* __restrict__ h,
    const float* __restrict__ W, const float* __restrict__ U,
    unsigned short* __restrict__ vb, unsigned short* __restrict__ hb,
    unsigned short* __restrict__ WT, unsigned short* __restrict__ UT) {
  int task = blockIdx.x * 256 + threadIdx.x;
  if (task < NT_V) {
    float4 x = ((const float4*)v)[task];
    ushort4 o = make_ushort4(f2bf(x.x), f2bf(x.y), f2bf(x.z), f2bf(x.w));
    *(ushort4*)&vb[(size_t)task * 4] = o;
  } else if (task < NT_V + NT_H) {
    int t2 = task - NT_V;
    float4 x = ((const float4*)h)[t2];
    ushort4 o = make_ushort4(f2bf(x.x), f2bf(x.y), f2bf(x.z), f2bf(x.w));
    *(ushort4*)&hb[(size_t)t2 * 4] = o;
  } else {
    int t2 = task - NT_V - NT_H;
    const float* S;
    unsigned short* Dt;
    if (t2 < NT_W) { S = W; Dt = WT; } else { S = U; Dt = UT; t2 -= NT_W; }
    int n = t2 & 255, k4 = t2 >> 8;           // k4 in [0,128)
    float a0 = S[(k4 * 4 + 0) * 256 + n];     // coalesced over n
    float a1 = S[(k4 * 4 + 1) * 256 + n];
    float a2 = S[(k4 * 4 + 2) * 256 + n];
    float a3 = S[(k4 * 4 + 3) * 256 + n];
    ushort4 o = make_ushort4(f2bf(a0), f2bf(a1), f2bf(a2), f2bf(a3));
    *(ushort4*)&Dt[(size_t)n * 512 + k4 * 4] = o;
  }
}

// ---------------------------------------------------------------------------
// MFMA GEMM, no LDS, no barriers. 384 blocks * 128 thr (2 waves).
//   blocks [0,256):   Wv2T[b][d][t] = (v @ W)^T-per-b * LOG2E2   (TRANSPOSED)
//   blocks [256,384): Uh2[m][d]     = (h @ U + b) * LOG2E2       (row-major)
// Wave tile: 32m x 32n x 512k via 2x2 of mfma_f32_16x16x32_bf16.
// C/D: col = l&15, row = (l>>4)*4 + reg   (m89-verified)
// Wv block spans rows [m0, m0+64) which lie inside one b (128-row granule),
// so b = m0>>7 and t = m&127 are block-uniform bases.
// ---------------------------------------------------------------------------
__global__ __launch_bounds__(128) void mfma_gemm_kernel(
    const unsigned short* __restrict__ Av, const unsigned short* __restrict__ Ah,
    const unsigned short* __restrict__ WT, const unsigned short* __restrict__ UT,
    const float* __restrict__ bias, float* __restrict__ Wv2T,
    float* __restrict__ Uh2) {
  const int bid = blockIdx.x;
  const unsigned short* A;
  const unsigned short* BT;
  int mt, nt;
  bool is_wv;
  if (bid < 256) {
    A = Av; BT = WT; is_wv = true;
    mt = bid >> 3; nt = bid & 7;
  } else {
    const int b2 = bid - 256;
    A = Ah; BT = UT; is_wv = false;
    mt = b2 >> 3; nt = b2 & 7;
  }
  const int wv   = threadIdx.x >> 6;   // 0..1
  const int lane = threadIdx.x & 63;
  const int m0   = mt * 64 + wv * 32;
  const int n0   = nt * 32;
  const int r16  = lane & 15;
  const int quad = lane >> 4;

  const unsigned short* a0p = A + (size_t)(m0 + r16) * 512 + quad * 8;
  const unsigned short* a1p = a0p + 16 * 512;
  const unsigned short* b0p = BT + (size_t)(n0 + r16) * 512 + quad * 8;
  const unsigned short* b1p = b0p + 16 * 512;

  f32x4 acc00 = {0.f, 0.f, 0.f, 0.f};
  f32x4 acc01 = {0.f, 0.f, 0.f, 0.f};
  f32x4 acc10 = {0.f, 0.f, 0.f, 0.f};
  f32x4 acc11 = {0.f, 0.f, 0.f, 0.f};

#pragma unroll
  for (int kc = 0; kc < 16; kc++) {
    bf16x8 a0 = *(const bf16x8*)(a0p + kc * 32);
    bf16x8 a1 = *(const bf16x8*)(a1p + kc * 32);
    bf16x8 b0 = *(const bf16x8*)(b0p + kc * 32);
    bf16x8 b1 = *(const bf16x8*)(b1p + kc * 32);
    acc00 = __builtin_amdgcn_mfma_f32_16x16x32_bf16(a0, b0, acc00, 0, 0, 0);
    acc01 = __builtin_amdgcn_mfma_f32_16x16x32_bf16(a0, b1, acc01, 0, 0, 0);
    acc10 = __builtin_amdgcn_mfma_f32_16x16x32_bf16(a1, b0, acc10, 0, 0, 0);
    acc11 = __builtin_amdgcn_mfma_f32_16x16x32_bf16(a1, b1, acc11, 0, 0, 0);
  }

  if (is_wv) {
    // transposed store: Wv2T[b*32768 + d*128 + t], d = n-col, t = m&127
    const int bb   = m0 >> 7;
    const int tb   = (m0 & 127) + quad * 4;       // + r below
    float* Wb = Wv2T + (size_t)bb * 32768;
#pragma unroll
    for (int r = 0; r < 4; r++) {
      Wb[(size_t)(n0 + r16) * 128 + tb + r]        = acc00[r] * LOG2E2;
      Wb[(size_t)(n0 + 16 + r16) * 128 + tb + r]   = acc01[r] * LOG2E2;
      Wb[(size_t)(n0 + r16) * 128 + tb + 16 + r]   = acc10[r] * LOG2E2;
      Wb[(size_t)(n0 + 16 + r16) * 128 + tb + 16 + r] = acc11[r] * LOG2E2;
    }
  } else {
    const float bj0 = bias[n0 + r16];
    const float bj1 = bias[n0 + 16 + r16];
#pragma unroll
    for (int r = 0; r < 4; r++) {
      const int row0 = m0 + quad * 4 + r;
      Uh2[(size_t)row0 * 256 + n0 + r16]             = (acc00[r] + bj0) * LOG2E2;
      Uh2[(size_t)row0 * 256 + n0 + 16 + r16]        = (acc01[r] + bj1) * LOG2E2;
      Uh2[(size_t)(row0 + 16) * 256 + n0 + r16]      = (acc10[r] + bj0) * LOG2E2;
      Uh2[(size_t)(row0 + 16) * 256 + n0 + 16 + r16] = (acc11[r] + bj1) * LOG2E2;
    }
  }
}

// ---------------------------------------------------------------------------
// Fused attention. 256 blocks = (b:16)x(sg:16), 4 s-rows/block, 1024 thr.
// Score: thread = (s:4, dg:8, t4:32); per d it loads Wv2T[d][4t] as float4
//   (lanes t4 consecutive -> contiguous 512 B segments), computes 4 sigmoids,
//   accumulates 4 t-partials over its 32 d's; partials reduced via pS LDS.
//   q[s,t](log2-domain) = -LOG2E2 * sum_dg partial
// Softmax over t: threads<512, wave shuffle + 2-wave LDS combine.
// Context: thread = (f:512, sh:2), coalesced v reads, broadcast beta.
// ---------------------------------------------------------------------------
__global__ __launch_bounds__(1024) void attn_fused_kernel(
    const float* __restrict__ Wv2T, const float* __restrict__ Uh2,
    const float* __restrict__ wg, const float* __restrict__ v,
    float* __restrict__ u) {
  __shared__ float UhS[4 * 256];
  __shared__ float wS[256];
  __shared__ float pS[4 * 1024];   // [s][dg][t]
  __shared__ float bS[4 * 128];
  __shared__ float mW[8];
  __shared__ float sW[8];

  const int tid = threadIdx.x;
  const int b   = blockIdx.x >> 4;
  const int sg  = blockIdx.x & 15;
  const int s0  = sg * 4;

  // ---- stage Uh (4x256) and w (256) ----
  if (tid < 256) {
    const int row = tid >> 6, q4 = (tid & 63) << 2;
    *(float4*)&UhS[row * 256 + q4] =
        *(const float4*)&Uh2[(size_t)(b * 64 + s0 + row) * 256 + q4];
  } else if (tid < 320) {
    const int q4 = (tid - 256) << 2;
    *(float4*)&wS[q4] = *(const float4*)&wg[q4];
  }
  __syncthreads();

  // ---- scores: thread = (s, dg, t4); 32 d x 4 t each ----
  {
    const int t4 = tid & 31;
    const int dg = (tid >> 5) & 7;
    const int s  = tid >> 8;
    const float* wvb = Wv2T + (size_t)b * 32768 + (size_t)dg * 32 * 128 + t4 * 4;
    const float* uhp = &UhS[s * 256 + dg * 32];
    const float* wp  = &wS[dg * 32];
    float4 acc = {0.f, 0.f, 0.f, 0.f};
#pragma unroll 8
    for (int j = 0; j < 32; j++) {
      float4 a  = *(const float4*)(wvb + j * 128);
      float uh = uhp[j];
      float ww = wp[j];
      acc.x = fmaf(ww, fast_rcp(fast_exp2(a.x + uh) + 1.0f), acc.x);
      acc.y = fmaf(ww, fast_rcp(fast_exp2(a.y + uh) + 1.0f), acc.y);
      acc.z = fmaf(ww, fast_rcp(fast_exp2(a.z + uh) + 1.0f), acc.z);
      acc.w = fmaf(ww, fast_rcp(fast_exp2(a.w + uh) + 1.0f), acc.w);
    }
    *(float4*)&pS[s * 1024 + dg * 128 + t4 * 4] = acc;
  }
  __syncthreads();

  // ---- reduce over dg + softmax over t (threads < 512) ----
  float qv = 0.0f, ev = 0.0f;
  const int wvid = tid >> 6, lane = tid & 63;
  if (tid < 512) {
    const int s_l = tid >> 7, t = tid & 127;
    float ssum = 0.0f;
#pragma unroll
    for (int dg = 0; dg < 8; dg++) ssum += pS[s_l * 1024 + dg * 128 + t];
    qv = ssum * (-LOG2E2);   // log2-domain score
    float m = qv;
#pragma unroll
    for (int off = 32; off > 0; off >>= 1) m = fmaxf(m, __shfl_xor(m, off, 64));
    if (lane == 0) mW[wvid] = m;
  }
  __syncthreads();
  if (tid < 512) {
    float m = fmaxf(mW[wvid], mW[wvid ^ 1]);
    ev = fast_exp2(qv - m);
    float ssum = ev;
#pragma unroll
    for (int off = 32; off > 0; off >>= 1) ssum += __shfl_xor(ssum, off, 64);
    if (lane == 0) sW[wvid] = ssum;
  }
  __syncthreads();
  if (tid < 512) {
    const int s_l = tid >> 7, t = tid & 127;
    bS[s_l * 128 + t] = ev * fast_rcp(sW[wvid] + sW[wvid ^ 1]);
  }
  __syncthreads();

  // ---- context: thread = (f:512, sh:2); 2 s-rows each ----
  const float* vb2 = v + (size_t)b * TV * FF;
  const int f  = tid & 511;
  const int sh = tid >> 9;
  float a0 = 0.f, a1 = 0.f;
#pragma unroll 4
  for (int tg = 0; tg < 128; tg += 4) {
    float4 b0 = *(const float4*)&bS[(sh * 2 + 0) * 128 + tg];
    float4 b1 = *(const float4*)&bS[(sh * 2 + 1) * 128 + tg];
    float v0 = vb2[(tg + 0) * 512 + f];
    float v1 = vb2[(tg + 1) * 512 + f];
    float v2 = vb2[(tg + 2) * 512 + f];
    float v3 = vb2[(tg + 3) * 512 + f];
    a0 = fmaf(b0.x, v0, a0); a0 = fmaf(b0.y, v1, a0);
    a0 = fmaf(b0.z, v2, a0); a0 = fmaf(b0.w, v3, a0);
    a1 = fmaf(b1.x, v0, a1); a1 = fmaf(b1.y, v1, a1);
    a1 = fmaf(b1.z, v2, a1); a1 = fmaf(b1.w, v3, a1);
  }
  float* urow = u + (size_t)(b * 64 + s0 + sh * 2) * 512;
  urow[0 * 512 + f] = a0;
  urow[1 * 512 + f] = a1;
}

extern "C" void kernel_launch(void* const* d_in, const int* in_sizes, int n_in,
                              void* d_out, int out_size, void* d_ws, size_t ws_size,
                              hipStream_t stream) {
  const float* v  = (const float*)d_in[0];  // [16,128,512]
  const float* h  = (const float*)d_in[1];  // [16,64,512]
  const float* W  = (const float*)d_in[2];  // [512,256]
  const float* U  = (const float*)d_in[3];  // [512,256]
  const float* bb = (const float*)d_in[4];  // [256]
  const float* w  = (const float*)d_in[5];  // [256,1]
  float* u = (float*)d_out;                 // [16,64,512]

  float* Wv2T = (float*)d_ws;                      // [16][256][128] f32 prescaled
  float* Uh2  = Wv2T + (size_t)2048 * 256;         // [1024,256] f32 prescaled
  unsigned short* vb16 = (unsigned short*)(Uh2 + (size_t)1024 * 256);
  unsigned short* hb16 = vb16 + (size_t)2048 * 512;  // bf16 copies
  unsigned short* WT   = hb16 + (size_t)1024 * 512;  // [256][512] bf16 (W^T)
  unsigned short* UT   = WT + (size_t)256 * 512;     // [256][512] bf16 (U^T)

  convert_kernel<<<1792, 256, 0, stream>>>(v, h, W, U, vb16, hb16, WT, UT);
  mfma_gemm_kernel<<<384, 128, 0, stream>>>(vb16, hb16, WT, UT, bb, Wv2T, Uh2);
  attn_fused_kernel<<<256, 1024, 0, stream>>>(Wv2T, Uh2, w, v, u);
}